// Round 12
// baseline (178.960 us; speedup 1.0000x reference)
//
#include <hip/hip_runtime.h>

// SDF volume rendering (NeuS/VolSDF-style), float32 in/out.
//
// Per ray (96 samples):
//   alpha_i = 1 - exp(-beta * sigmoid(-sdf_i * beta))
//   t_i     = 1 - alpha_i + 1e-10
//   trans_i = exclusive cumprod of t ;  w_i = alpha_i * trans_i
//   depth   = sum w_i * z_i ;  rgb_c = sum w_i * rgb_{i,c}
//
// R16: Little's-law accounting finally fits every data point. 2.8 TB/s at
// ~375ns latency needs ~4.1 KB/CU in flight; our compute waves carry 4 KB
// EACH but only during their single ~900cy load-wait, then go memory-silent
// for 1.5-2k cy (serial exp/shfl) and die -> ~1 waiting wave/CU -> 2.8 TB/s,
// invariant to scheduling (R5/R9/R12/R14/R15 all ~4 KB/wave). The copy
// kernel's 7.7 TB/s comes from 32 resident waves at ~100% load-duty.
// R11 tried 4x bytes/wave but the allocator refused (VGPR 48 < 60 needed).
// R13 proved asm keep-alive FORCES liveness. Combine them:
//   * 4 rays per lane-group: 20 dwordx3 loads, 240 B/thread = 15.4 KB/wave
//     issued back-to-back, then 4x 15-operand "+v" keep-alives (all 60
//     floats simultaneously live -- serialization impossible).
//   * one vmcnt drain, then 4 sequential compute+store phases; all stores
//     AFTER all loads (in-order vmcnt cannot poison).
//   * launch_bounds(256,4): ~80 VGPR -> ~24 waves/CU each parked with
//     15.4 KB outstanding.
// Copy stays a separate proven dispatch (~13us at 7.7 TB/s).
// Validation: VGPR_Count must jump to ~72-88, compute ~45 -> 22-30us.

#define SDFR_NS 96
#define SDFR_RPB 32     // rays per compute block: 8 lane-groups x 4 rays

struct f3 { float x, y, z; };                              // 12B -> dwordx3
typedef float fv4 __attribute__((ext_vector_type(4)));     // true vector type

__device__ __forceinline__ void compute_ray(
    int l, float beta,
    const f3& sv, const f3& zv, const f3& ca, const f3& cb, const f3& cc,
    float& depth, float& r0, float& r1, float& r2)
{
    // sigmoid(-s*beta) = 1/(1+exp(s*beta)); e = exp(-beta*sig)
    const float e0 = __expf(-beta * __builtin_amdgcn_rcpf(1.0f + __expf(sv.x * beta)));
    const float e1 = __expf(-beta * __builtin_amdgcn_rcpf(1.0f + __expf(sv.y * beta)));
    const float e2 = __expf(-beta * __builtin_amdgcn_rcpf(1.0f + __expf(sv.z * beta)));
    const float a0 = 1.0f - e0, t0 = e0 + 1e-10f;
    const float a1 = 1.0f - e1, t1 = e1 + 1e-10f;
    const float a2 = 1.0f - e2, t2 = e2 + 1e-10f;

    // 32-lane exclusive prefix product of per-lane local product
    float scan = t0 * t1 * t2;
    #pragma unroll
    for (int d = 1; d < 32; d <<= 1) {
        float v = __shfl_up(scan, d, 32);
        if (l >= d) scan *= v;
    }
    float E = __shfl_up(scan, 1, 32);
    if (l == 0) E = 1.0f;

    const float w0 = a0 * E;
    const float w1 = a1 * E * t0;
    const float w2 = a2 * E * t0 * t1;

    depth = w0 * zv.x + w1 * zv.y + w2 * zv.z;
    r0    = w0 * ca.x + w1 * cb.x + w2 * cc.x;
    r1    = w0 * ca.y + w1 * cb.y + w2 * cc.y;
    r2    = w0 * ca.z + w1 * cb.z + w2 * cc.z;

    #pragma unroll
    for (int d = 16; d >= 1; d >>= 1) {
        depth += __shfl_xor(depth, d, 32);
        r0    += __shfl_xor(r0, d, 32);
        r1    += __shfl_xor(r1, d, 32);
        r2    += __shfl_xor(r2, d, 32);
    }
}

// ---------------------------------------------------------------- compute --
__global__ __launch_bounds__(256, 4) void sdf_compute_kernel(
    const float* __restrict__ rgb,      // [N*96*3]
    const float* __restrict__ sdf,      // [N*96]
    const float* __restrict__ z_vals,   // [N*96]
    const int*   __restrict__ beta_p,
    float* __restrict__ out_depth,      // [N]
    float* __restrict__ out_rgb,        // [N,3]
    int n_rays)
{
    const int t    = threadIdx.x;
    const int g    = t >> 5;          // lane-group 0..7
    const int l    = t & 31;          // lane l owns samples [3l, 3l+3)
    const int base = blockIdx.x * SDFR_RPB;

    // beta decode: small int is the value; huge magnitude is an f32 pattern
    int bi = *beta_p;
    float beta;
    if (bi > 1000000 || bi < -1000000) {
        union { int i; float f; } u; u.i = bi; beta = u.f;
    } else {
        beta = (float)bi;
    }

    f3 sv0, zv0, ca0, cb0, cc0;
    f3 sv1, zv1, ca1, cb1, cc1;
    f3 sv2, zv2, ca2, cb2, cc2;
    f3 sv3, zv3, ca3, cb3, cc3;

#define SDFR_LOAD(K, RAY)                                           \
    do {                                                            \
        const int sb_ = (RAY) * SDFR_NS + 3 * l;                    \
        const int rb_ = (RAY) * (SDFR_NS * 3) + 9 * l;              \
        sv##K = *(const f3*)(sdf    + sb_);                         \
        zv##K = *(const f3*)(z_vals + sb_);                         \
        ca##K = *(const f3*)(rgb + rb_ + 0);                        \
        cb##K = *(const f3*)(rgb + rb_ + 3);                        \
        cc##K = *(const f3*)(rgb + rb_ + 6);                        \
    } while (0)

// keep-alive: 15 floats of one ray-set simultaneously live (R13-proven).
#define SDFR_PIN(K)                                                 \
    asm volatile("" :                                               \
        "+v"(sv##K.x), "+v"(sv##K.y), "+v"(sv##K.z),                \
        "+v"(zv##K.x), "+v"(zv##K.y), "+v"(zv##K.z),                \
        "+v"(ca##K.x), "+v"(ca##K.y), "+v"(ca##K.z),                \
        "+v"(cb##K.x), "+v"(cb##K.y), "+v"(cb##K.z),                \
        "+v"(cc##K.x), "+v"(cc##K.y), "+v"(cc##K.z))

#define SDFR_RUN(K, RAY)                                            \
    do {                                                            \
        float d_, x_, y_, w_;                                       \
        compute_ray(l, beta, sv##K, zv##K, ca##K, cb##K, cc##K,     \
                    d_, x_, y_, w_);                                \
        if (l == 0) {                                               \
            out_depth[(RAY)] = d_;                                  \
            f3 o_; o_.x = x_; o_.y = y_; o_.z = w_;                 \
            *(f3*)(out_rgb + (RAY) * 3) = o_;                       \
        }                                                           \
    } while (0)

    if (base + SDFR_RPB <= n_rays) {
        const int r0_ = base + g;
        const int r1_ = r0_ + 8;
        const int r2_ = r0_ + 16;
        const int r3_ = r0_ + 24;

        // all 20 loads issued back-to-back: 240 B/thread = 15.4 KB/wave
        SDFR_LOAD(0, r0_);
        SDFR_LOAD(1, r1_);
        SDFR_LOAD(2, r2_);
        SDFR_LOAD(3, r3_);
        __builtin_amdgcn_sched_barrier(0);

        // force all 60 result floats simultaneously live
        SDFR_PIN(0);
        SDFR_PIN(1);
        SDFR_PIN(2);
        SDFR_PIN(3);

        // 4 sequential compute+store phases; no loads after any store
        SDFR_RUN(0, r0_);
        SDFR_RUN(1, r1_);
        SDFR_RUN(2, r2_);
        SDFR_RUN(3, r3_);
    } else {
        // tail path (never taken at N=65536): guarded, unbatched
        for (int p = 0; p < 4; ++p) {
            const int ray = base + p * 8 + g;
            if (ray < n_rays) {
                SDFR_LOAD(0, ray);
                SDFR_RUN(0, ray);
            }
        }
    }

#undef SDFR_LOAD
#undef SDFR_PIN
#undef SDFR_RUN
}

// ------------------------------------------------------------------- copy --
#define SDFR_CPB 2048   // copy grid: 2048 blocks x 256 thr (ubench shape)

__global__ __launch_bounds__(256, 8) void sdf_copy_kernel(
    const float* __restrict__ sdf,
    const float* __restrict__ z_vals,
    float* __restrict__ out_sdf,
    float* __restrict__ out_z,
    int n_rays)
{
    const int n4     = (n_rays * SDFR_NS) / 4;   // 1,572,864 @ N=65536
    const int stride = SDFR_CPB * 256;           // 524,288 -> 3 iters
    const fv4* __restrict__ s4 = (const fv4*)sdf;
    const fv4* __restrict__ z4 = (const fv4*)z_vals;
    fv4* __restrict__ os4 = (fv4*)out_sdf;
    fv4* __restrict__ oz4 = (fv4*)out_z;

    for (int i = blockIdx.x * 256 + threadIdx.x; i < n4; i += stride) {
        const fv4 a = s4[i];
        const fv4 b = z4[i];
        __builtin_nontemporal_store(a, os4 + i);
        __builtin_nontemporal_store(b, oz4 + i);
    }
}

extern "C" void kernel_launch(void* const* d_in, const int* in_sizes, int n_in,
                              void* d_out, int out_size, void* d_ws, size_t ws_size,
                              hipStream_t stream) {
    (void)n_in; (void)d_ws; (void)ws_size; (void)out_size;

    const float* rgb    = (const float*)d_in[0];
    const float* sdf    = (const float*)d_in[1];
    const float* z      = (const float*)d_in[2];
    const int*   beta_p = (const int*)d_in[3];

    const int n_rays = in_sizes[1] / SDFR_NS;  // 65536

    // output layout (f32): depth[N] | rgb[N*3] | sdf[N*96] | z[N*96]
    float* out_depth = (float*)d_out;
    float* out_rgb   = out_depth + n_rays;
    float* out_sdf   = out_rgb   + (size_t)n_rays * 3;
    float* out_z     = out_sdf   + (size_t)n_rays * SDFR_NS;

    // K1 first: its sdf/z reads leave them L3-hot for K2's copy.
    const int comp_blocks = (n_rays + SDFR_RPB - 1) / SDFR_RPB;   // 2048
    sdf_compute_kernel<<<comp_blocks, 256, 0, stream>>>(
        rgb, sdf, z, beta_p, out_depth, out_rgb, n_rays);

    sdf_copy_kernel<<<SDFR_CPB, 256, 0, stream>>>(
        sdf, z, out_sdf, out_z, n_rays);
}

// Round 13
// 177.314 us; speedup vs baseline: 1.0093x; 1.0093x over previous
//
#include <hip/hip_runtime.h>

// SDF volume rendering (NeuS/VolSDF-style), float32 in/out.
//
// Per ray (96 samples):
//   alpha_i = 1 - exp(-beta * sigmoid(-sdf_i * beta))
//   t_i     = 1 - alpha_i + 1e-10
//   trans_i = exclusive cumprod of t ;  w_i = alpha_i * trans_i
//   depth   = sum w_i * z_i ;  rgb_c = sum w_i * rgb_{i,c}
//
// R17: R16 falsified register-parking: 4x volatile keep-alives still gave
// VGPR=40 (<60 needed) -- the allocator sinks/interleaves loads no matter
// what; R5/R11/R13/R16 all lost this fight. The un-tried mechanism is
// ZERO-REGISTER staging: __builtin_amdgcn_global_load_lds (16B/lane DMA,
// no data VGPRs, nothing to serialize). Per 8-ray block: 15 slots x 1024B
// (sdf 3K | z 3K | rgb 9K), 3-4 issues/wave, ONE vmcnt(0)+barrier, compute
// from LDS (stride-3/9 reads, gcd(.,32)=1 + free 2-way wave64 aliasing =
// conflict-free). In-flight bytes/CU = 8 blocks x 15KB = 120KB (~30x the
// ~4KB/wave register path) -- the copy-kernel regime without regalloc.
// XCD-chunked swizzle (8192%8==0, bijective) for contiguous per-XCD reads.
// Copy dispatch unchanged (R12-proven).

#define SDFR_NS 96
#define SDFR_RPB 8      // rays per compute block (256 thr, 32 lanes/ray)

typedef float fv4 __attribute__((ext_vector_type(4)));     // true vector type
struct f3 { float x, y, z; };

// ---------------------------------------------------------------- compute --
__global__ __launch_bounds__(256, 8) void sdf_compute_kernel(
    const float* __restrict__ rgb,      // [N*96*3]
    const float* __restrict__ sdf,      // [N*96]
    const float* __restrict__ z_vals,   // [N*96]
    const int*   __restrict__ beta_p,
    float* __restrict__ out_depth,      // [N]
    float* __restrict__ out_rgb,        // [N,3]
    int n_rays)
{
    // [0,768) sdf | [768,1536) z | [1536,3840) rgb   (floats; 15360 B)
    __shared__ __align__(16) float lds[SDFR_RPB * SDFR_NS * 5];

    const int t = threadIdx.x;

    // XCD-chunked bijective swizzle: each XCD reads a contiguous 1/8
    const int cpx = (int)(gridDim.x >> 3);
    const int blk = (int)((blockIdx.x & 7) * cpx + (blockIdx.x >> 3));

    const int base_ray = blk * SDFR_RPB;
    const int g   = t >> 5;          // ray within block, 0..7
    const int l   = t & 31;          // lane l owns samples [3l, 3l+3)
    const int ray = base_ray + g;

    const bool full = (base_ray + SDFR_RPB <= n_rays);

    if (full) {
        // ---- zero-register staging: 15 x 1024B global->LDS DMA slots ----
        // wave w handles slots {w, w+4, w+8, w+12<15}; no data VGPRs, all
        // slots outstanding together; one vmcnt(0) at the barrier.
        const int lane = t & 63;     // wave64 lane
        const int w    = t >> 6;     // wave id 0..3
        char* lb = (char*)lds;
        #pragma unroll
        for (int k = 0; k < 4; ++k) {
            const int s = w + k * 4;             // wave-uniform slot id
            if (s < 15) {
                const char* src;
                if (s < 3)
                    src = (const char*)sdf    + (size_t)blk * 3072 + (size_t)s * 1024;
                else if (s < 6)
                    src = (const char*)z_vals + (size_t)blk * 3072 + (size_t)(s - 3) * 1024;
                else
                    src = (const char*)rgb    + (size_t)blk * 9216 + (size_t)(s - 6) * 1024;
                __builtin_amdgcn_global_load_lds(
                    (const __attribute__((address_space(1))) void*)(src + lane * 16),
                    (__attribute__((address_space(3))) void*)(lb + s * 1024),
                    16, 0, 0);
            }
        }
    } else {
        // tail path (never taken at N=65536): guarded cooperative copy
        const int flim = n_rays * SDFR_NS;
        for (int i = t; i < SDFR_RPB * SDFR_NS; i += 256) {
            const int gi = base_ray * SDFR_NS + i;
            lds[i]       = (gi < flim) ? sdf[gi]    : 0.f;
            lds[768 + i] = (gi < flim) ? z_vals[gi] : 0.f;
        }
        const int clim = n_rays * SDFR_NS * 3;
        for (int i = t; i < SDFR_RPB * SDFR_NS * 3; i += 256) {
            const int gi = base_ray * SDFR_NS * 3 + i;
            lds[1536 + i] = (gi < clim) ? rgb[gi] : 0.f;
        }
    }

    __syncthreads();
    if (ray >= n_rays) return;

    // ---- compute from LDS; stride-3/9 reads, conflict-free ----
    const float* sf = lds + g * SDFR_NS + 3 * l;
    const float* zf = lds + 768 + g * SDFR_NS + 3 * l;
    const float* cf = lds + 1536 + g * (SDFR_NS * 3) + 9 * l;
    const float s0 = sf[0], s1 = sf[1], s2 = sf[2];
    const float z0 = zf[0], z1 = zf[1], z2 = zf[2];
    const float c0 = cf[0], c1 = cf[1], c2 = cf[2];
    const float c3 = cf[3], c4 = cf[4], c5 = cf[5];
    const float c6 = cf[6], c7 = cf[7], c8 = cf[8];

    // beta decode: small int is the value; huge magnitude is an f32 pattern
    int bi = *beta_p;
    float beta;
    if (bi > 1000000 || bi < -1000000) {
        union { int i; float f; } u; u.i = bi; beta = u.f;
    } else {
        beta = (float)bi;
    }

    // sigmoid(-s*beta) = 1/(1+exp(s*beta)); e = exp(-beta*sig)
    const float e0 = __expf(-beta * __builtin_amdgcn_rcpf(1.0f + __expf(s0 * beta)));
    const float e1 = __expf(-beta * __builtin_amdgcn_rcpf(1.0f + __expf(s1 * beta)));
    const float e2 = __expf(-beta * __builtin_amdgcn_rcpf(1.0f + __expf(s2 * beta)));
    const float a0 = 1.0f - e0, t0 = e0 + 1e-10f;
    const float a1 = 1.0f - e1, t1 = e1 + 1e-10f;
    const float a2 = 1.0f - e2, t2 = e2 + 1e-10f;

    // 32-lane exclusive prefix product of per-lane local product
    float scan = t0 * t1 * t2;
    #pragma unroll
    for (int d = 1; d < 32; d <<= 1) {
        float v = __shfl_up(scan, d, 32);
        if (l >= d) scan *= v;
    }
    float E = __shfl_up(scan, 1, 32);
    if (l == 0) E = 1.0f;

    const float w0 = a0 * E;
    const float w1 = a1 * E * t0;
    const float w2 = a2 * E * t0 * t1;

    float depth = w0 * z0 + w1 * z1 + w2 * z2;
    float r0    = w0 * c0 + w1 * c3 + w2 * c6;
    float r1    = w0 * c1 + w1 * c4 + w2 * c7;
    float r2    = w0 * c2 + w1 * c5 + w2 * c8;

    #pragma unroll
    for (int d = 16; d >= 1; d >>= 1) {
        depth += __shfl_xor(depth, d, 32);
        r0    += __shfl_xor(r0, d, 32);
        r1    += __shfl_xor(r1, d, 32);
        r2    += __shfl_xor(r2, d, 32);
    }

    // only stores: 16B per ray, at wave end
    if (l == 0) {
        out_depth[ray] = depth;
        f3 o; o.x = r0; o.y = r1; o.z = r2;
        *(f3*)(out_rgb + ray * 3) = o;
    }
}

// ------------------------------------------------------------------- copy --
#define SDFR_CPB 2048   // copy grid: 2048 blocks x 256 thr (ubench shape)

__global__ __launch_bounds__(256, 8) void sdf_copy_kernel(
    const float* __restrict__ sdf,
    const float* __restrict__ z_vals,
    float* __restrict__ out_sdf,
    float* __restrict__ out_z,
    int n_rays)
{
    const int n4     = (n_rays * SDFR_NS) / 4;   // 1,572,864 @ N=65536
    const int stride = SDFR_CPB * 256;           // 524,288 -> 3 iters
    const fv4* __restrict__ s4 = (const fv4*)sdf;
    const fv4* __restrict__ z4 = (const fv4*)z_vals;
    fv4* __restrict__ os4 = (fv4*)out_sdf;
    fv4* __restrict__ oz4 = (fv4*)out_z;

    for (int i = blockIdx.x * 256 + threadIdx.x; i < n4; i += stride) {
        const fv4 a = s4[i];
        const fv4 b = z4[i];
        __builtin_nontemporal_store(a, os4 + i);
        __builtin_nontemporal_store(b, oz4 + i);
    }
}

extern "C" void kernel_launch(void* const* d_in, const int* in_sizes, int n_in,
                              void* d_out, int out_size, void* d_ws, size_t ws_size,
                              hipStream_t stream) {
    (void)n_in; (void)d_ws; (void)ws_size; (void)out_size;

    const float* rgb    = (const float*)d_in[0];
    const float* sdf    = (const float*)d_in[1];
    const float* z      = (const float*)d_in[2];
    const int*   beta_p = (const int*)d_in[3];

    const int n_rays = in_sizes[1] / SDFR_NS;  // 65536

    // output layout (f32): depth[N] | rgb[N*3] | sdf[N*96] | z[N*96]
    float* out_depth = (float*)d_out;
    float* out_rgb   = out_depth + n_rays;
    float* out_sdf   = out_rgb   + (size_t)n_rays * 3;
    float* out_z     = out_sdf   + (size_t)n_rays * SDFR_NS;

    // K1 first: its sdf/z reads leave them L3-hot for K2's copy.
    const int comp_blocks = (n_rays + SDFR_RPB - 1) / SDFR_RPB;   // 8192
    sdf_compute_kernel<<<comp_blocks, 256, 0, stream>>>(
        rgb, sdf, z, beta_p, out_depth, out_rgb, n_rays);

    sdf_copy_kernel<<<SDFR_CPB, 256, 0, stream>>>(
        sdf, z, out_sdf, out_z, n_rays);
}